// Round 5
// baseline (758.452 us; speedup 1.0000x reference)
//
#include <hip/hip_runtime.h>
#include <hip/hip_bf16.h>

// GAT round 4: attention P-gen exp-factorization (E1=2^dst precomputed per block,
// E2=E1^0.01 via int pow trick), LDS diet -> 3 blocks/CU. Rest unchanged from R3.

#define NN 4096
#define FF 512
#define HH 256
#define KK 8
#define KH 2048  // KK*HH

typedef __attribute__((ext_vector_type(8))) short bf16x8;
typedef __attribute__((ext_vector_type(4))) float f32x4;
typedef __attribute__((ext_vector_type(16))) float f32x16;

__device__ inline short f2bf(float x) {
    __hip_bfloat16 b = __float2bfloat16(x);
    return *reinterpret_cast<short*>(&b);
}
__device__ inline short to_bf(float x) { return f2bf(x); }
__device__ inline short to_bf(short x) { return x; }

// ---- adjacency: fp32 -> A-frag bf16 (exact) + mask bitpack, single 64MB read ----
__global__ __launch_bounds__(256) void cvt_adj_kernel(const float* __restrict__ adj,
                                                      bf16x8* __restrict__ Af,
                                                      unsigned int* __restrict__ mbits) {
    int t = threadIdx.x, lane = t & 63, w = t >> 6, mt = blockIdx.x;
    int m = mt * 16 + (lane & 15), kq = (lane >> 4) * 8;
    for (int kt = w; kt < 128; kt += 4) {
        size_t base = (size_t)m * NN + kt * 32 + kq;
        float4 f0 = *(const float4*)&adj[base];
        float4 f1 = *(const float4*)&adj[base + 4];
        bf16x8 v;
        v[0] = f2bf(f0.x); v[1] = f2bf(f0.y); v[2] = f2bf(f0.z); v[3] = f2bf(f0.w);
        v[4] = f2bf(f1.x); v[5] = f2bf(f1.y); v[6] = f2bf(f1.z); v[7] = f2bf(f1.w);
        Af[((size_t)mt * 128 + kt) * 64 + lane] = v;
    }
    for (int r = w; r < 16; r += 4) {
        int row = mt * 16 + r;
        for (int j0 = 0; j0 < NN; j0 += 64) {
            float vv = adj[(size_t)row * NN + j0 + lane];
            unsigned long long b = __ballot(vv == 1.0f);
            if (lane == 0) {
                mbits[row * 128 + (j0 >> 5)]     = (unsigned int)(b & 0xffffffffull);
                mbits[row * 128 + (j0 >> 5) + 1] = (unsigned int)(b >> 32);
            }
        }
    }
}

// ---- row-major [M][K] (fp32 or bf16 bits) -> A-frag bf16 (16x16x32 layout) ----
template <typename T>
__global__ __launch_bounds__(256) void cvt_a_frag_kernel(const T* __restrict__ src,
                                                         bf16x8* __restrict__ dst, int K) {
    int t = threadIdx.x, lane = t & 63, w = t >> 6, mt = blockIdx.x;
    int Kt = K >> 5;
    int m = mt * 16 + (lane & 15), kq = (lane >> 4) * 8;
    for (int kt = w; kt < Kt; kt += 4) {
        size_t base = (size_t)m * K + kt * 32 + kq;
        bf16x8 v;
#pragma unroll
        for (int jj = 0; jj < 8; jj++) v[jj] = to_bf(src[base + jj]);
        dst[((size_t)mt * Kt + kt) * 64 + lane] = v;
    }
}

// ---- W [N][K] row-major (B^T) fp32 -> B-frag bf16 ----
__global__ __launch_bounds__(256) void cvt_bt_frag_kernel(const float* __restrict__ Wm,
                                                          bf16x8* __restrict__ dst,
                                                          int K, int Nt) {
    int t = threadIdx.x, lane = t & 63, w = t >> 6, nt = blockIdx.x;
    int Kt = K >> 5;
    int n = nt * 16 + (lane & 15), kq = (lane >> 4) * 8;
    for (int kt = w; kt < Kt; kt += 4) {
        size_t base = (size_t)n * K + kt * 32 + kq;
        bf16x8 v;
#pragma unroll
        for (int jj = 0; jj < 8; jj++) v[jj] = f2bf(Wm[base + jj]);
        dst[((size_t)kt * Nt + nt) * 64 + lane] = v;
    }
}

// ---- src [K][W] fp32 -> B-frag bf16 (16x16x32 layout, LDS-staged) ----
template <int W>
__global__ __launch_bounds__(256) void cvt_b_frag_kernel(const float* __restrict__ src,
                                                         bf16x8* __restrict__ dst) {
    __shared__ float hs[32][W + 8];
    constexpr int Nt = W / 16;
    int t = threadIdx.x, jb = blockIdx.x;
    {
        int r = t >> 3, cb = (t & 7) * (W / 8);
        const float* sp = &src[(size_t)(jb * 32 + r) * W + cb];
#pragma unroll
        for (int q = 0; q < W / 32; q++) *(float4*)&hs[r][cb + q * 4] = *(const float4*)&sp[q * 4];
    }
    __syncthreads();
    for (int id = t; id < Nt * 64; id += 256) {
        int nt = id >> 6, lane = id & 63;
        int c = nt * 16 + (lane & 15), q8 = (lane >> 4) * 8;
        bf16x8 v;
#pragma unroll
        for (int jj = 0; jj < 8; jj++) v[jj] = f2bf(hs[q8 + jj][c]);
        dst[((size_t)jb * Nt + nt) * 64 + lane] = v;
    }
}

// ---- fragment-direct bf16 MFMA GEMM (16x16x32): C = A@B (+bias) ----
__global__ __launch_bounds__(256) void gemm_frag_kernel(
    const bf16x8* __restrict__ Af, const bf16x8* __restrict__ Bf,
    const float* __restrict__ bias, float* __restrict__ C,
    int Kt, int Nt, int Nrow) {
    int t = threadIdx.x, lane = t & 63, w = t >> 6;
    int quad = lane >> 4, c16 = lane & 15;
    int wm = w & 1, wn = w >> 1;
    int mt0 = blockIdx.y * 4 + wm * 2;
    int nt0 = blockIdx.x * 8 + wn * 4;
    f32x4 acc[2][4];
#pragma unroll
    for (int i = 0; i < 2; i++)
#pragma unroll
        for (int j = 0; j < 4; j++) acc[i][j] = (f32x4){0.f, 0.f, 0.f, 0.f};
    const bf16x8* ap = Af + (size_t)mt0 * Kt * 64 + lane;
    const bf16x8* bp = Bf + (size_t)nt0 * 64 + lane;
#pragma unroll 2
    for (int kt = 0; kt < Kt; kt++) {
        bf16x8 a0 = ap[(size_t)kt * 64];
        bf16x8 a1 = ap[((size_t)Kt + kt) * 64];
        bf16x8 b0 = bp[(size_t)kt * Nt * 64];
        bf16x8 b1 = bp[((size_t)kt * Nt + 1) * 64];
        bf16x8 b2 = bp[((size_t)kt * Nt + 2) * 64];
        bf16x8 b3 = bp[((size_t)kt * Nt + 3) * 64];
        acc[0][0] = __builtin_amdgcn_mfma_f32_16x16x32_bf16(a0, b0, acc[0][0], 0, 0, 0);
        acc[0][1] = __builtin_amdgcn_mfma_f32_16x16x32_bf16(a0, b1, acc[0][1], 0, 0, 0);
        acc[0][2] = __builtin_amdgcn_mfma_f32_16x16x32_bf16(a0, b2, acc[0][2], 0, 0, 0);
        acc[0][3] = __builtin_amdgcn_mfma_f32_16x16x32_bf16(a0, b3, acc[0][3], 0, 0, 0);
        acc[1][0] = __builtin_amdgcn_mfma_f32_16x16x32_bf16(a1, b0, acc[1][0], 0, 0, 0);
        acc[1][1] = __builtin_amdgcn_mfma_f32_16x16x32_bf16(a1, b1, acc[1][1], 0, 0, 0);
        acc[1][2] = __builtin_amdgcn_mfma_f32_16x16x32_bf16(a1, b2, acc[1][2], 0, 0, 0);
        acc[1][3] = __builtin_amdgcn_mfma_f32_16x16x32_bf16(a1, b3, acc[1][3], 0, 0, 0);
    }
#pragma unroll
    for (int i = 0; i < 2; i++) {
#pragma unroll
        for (int j = 0; j < 4; j++) {
            int n = (nt0 + j) * 16 + c16;
            float bv = bias ? bias[n] : 0.f;
#pragma unroll
            for (int reg = 0; reg < 4; reg++) {
                int m = (mt0 + i) * 16 + quad * 4 + reg;
                C[(size_t)m * Nrow + n] = acc[i][j][reg] + bv;
            }
        }
    }
}

// ---- prep: h -> HB32 (32x32x16 B-frag order) + srcT/dstT (log2e-scaled) ----
__global__ __launch_bounds__(256) void prep_kernel(const float* __restrict__ h,
                                                   const float* __restrict__ aw,
                                                   const float* __restrict__ ab,
                                                   bf16x8* __restrict__ HB32,
                                                   float* __restrict__ srcT,
                                                   float* __restrict__ dstT) {
    __shared__ __align__(16) float hs[32][264];
    __shared__ __align__(16) float awl[KK * 512];
    int t = threadIdx.x, jb = blockIdx.x;
#pragma unroll
    for (int q = 0; q < 4; q++)
        *(float4*)&awl[(t + q * 256) * 4] = *(const float4*)&aw[(t + q * 256) * 4];
    {
        int r = t >> 3, cb = (t & 7) * 32;
        const float* hp = &h[(size_t)(jb * 32 + r) * HH + cb];
#pragma unroll
        for (int q = 0; q < 8; q++) *(float4*)&hs[r][cb + q * 4] = *(const float4*)&hp[q * 4];
    }
    __syncthreads();
#pragma unroll
    for (int it = 0; it < 4; it++) {
        int id = t + it * 256;
        int q = id >> 9, nt = (id >> 6) & 7, lane = id & 63;
        int c = nt * 32 + (lane & 31), j8 = q * 16 + (lane >> 5) * 8;
        bf16x8 v;
#pragma unroll
        for (int jj = 0; jj < 8; jj++) v[jj] = f2bf(hs[j8 + jj][c]);
        HB32[((size_t)(jb * 2 + q)) * 512 + nt * 64 + lane] = v;
    }
    {
        const float LOG2E = 1.4426950408889634f;
        int row = t & 31, head = t >> 5;
        float s = ab[head], d = 0.f;
        const float* ws = &awl[head * 512];
        const float* wd = ws + 256;
#pragma unroll 4
        for (int c = 0; c < 256; c += 4) {
            float4 hv = *(const float4*)&hs[row][c];
            float4 a4 = *(const float4*)&ws[c];
            float4 b4 = *(const float4*)&wd[c];
            s += hv.x * a4.x + hv.y * a4.y + hv.z * a4.z + hv.w * a4.w;
            d += hv.x * b4.x + hv.y * b4.y + hv.z * b4.z + hv.w * b4.w;
        }
        srcT[head * NN + jb * 32 + row] = s * LOG2E;
        dstT[head * NN + jb * 32 + row] = d * LOG2E;
    }
}

// ---------------- per-head max of dst (scaled domain) ----------------
__global__ void maxdst_kernel(const float* __restrict__ dstT, float* __restrict__ maxd) {
    int k = blockIdx.x, t = threadIdx.x;
    float m = -1e30f;
    for (int i = t; i < NN; i += 256) m = fmaxf(m, dstT[(size_t)k * NN + i]);
    for (int off = 32; off > 0; off >>= 1) m = fmaxf(m, __shfl_down(m, off));
    __shared__ float red[4];
    if ((t & 63) == 0) red[t >> 6] = m;
    __syncthreads();
    if (t == 0) maxd[k] = fmaxf(fmaxf(red[0], red[1]), fmaxf(red[2], red[3]));
}

// ---- attention, 32x32x16 MFMA: block = 32 rows x 2 heads, 4 waves -----------
// P-gen via exp factorization: p = max(E1_j * A_row, E2_j * B_row), where
// E1[j]=2^dd_j precomputed in LDS once per block; E2=E1^0.01 via int pow trick;
// A=2^(s-m), B=2^(0.01s-m) per-row registers. No transcendentals in hot loop.
template <int MODE>
__global__ __launch_bounds__(256, 3) void attn32_kernel(
    const float* __restrict__ h, const float* __restrict__ srcT,
    const float* __restrict__ dstT, const float* __restrict__ maxd,
    const unsigned int* __restrict__ mbits, const bf16x8* __restrict__ HB32,
    void* __restrict__ outp) {
    __shared__ __align__(16) char smraw[49600];
    __shared__ float l_all[2][2][32];
    __shared__ float linv_l[2][32];
    float* e1 = (float*)smraw;                            // [2][4096] fp32 (loop)
    unsigned int* mrow = (unsigned int*)(smraw + 32768);  // [32*131]   (loop)
    float* accbuf = (float*)smraw;                        // [2ch][4nt][16][64] (epi, 32KB)

    int t = threadIdx.x;
    int i0 = blockIdx.x * 32;
    int k0 = blockIdx.y * 2;

#pragma unroll
    for (int q = 0; q < 8; q++) {
        int idx = t + q * 256;                // 0..2047 float4 units
        int hh = idx >> 10, off = (idx & 1023) * 4;
        float4 dv = *(const float4*)&dstT[(size_t)(k0 + hh) * NN + off];
        float4 ev;
        ev.x = __builtin_amdgcn_exp2f(dv.x);
        ev.y = __builtin_amdgcn_exp2f(dv.y);
        ev.z = __builtin_amdgcn_exp2f(dv.z);
        ev.w = __builtin_amdgcn_exp2f(dv.w);
        *(float4*)&e1[hh * 4096 + off] = ev;
    }
#pragma unroll
    for (int q = 0; q < 16; q++) {
        int idx = t + q * 256;                // 0..4095
        int r = idx >> 7, wd = idx & 127;
        mrow[r * 131 + wd] = mbits[(size_t)(i0 + r) * 128 + wd];
    }
    __syncthreads();

    int lane = t & 63, w = t >> 6;
    int jh = w & 1, ch = w >> 1;
    int rowl = lane & 31, jsub = (lane >> 5) * 8;

    float Ac[2], Bc[2], lacc[2] = {0.f, 0.f};
#pragma unroll
    for (int hh = 0; hh < 2; hh++) {
        float sL = srcT[(size_t)(k0 + hh) * NN + i0 + rowl];
        float xm = sL + maxd[k0 + hh];
        float mL = fmaxf(xm, 0.01f * xm);     // lrelu upper bound (log2 domain)
        Ac[hh] = __builtin_amdgcn_exp2f(sL - mL);
        Bc[hh] = __builtin_amdgcn_exp2f(fmaf(0.01f, sL, -mL));
    }

    f32x16 acc[2][4];
#pragma unroll
    for (int hh = 0; hh < 2; hh++)
#pragma unroll
        for (int nt = 0; nt < 4; nt++)
#pragma unroll
            for (int r = 0; r < 16; r++) acc[hh][nt][r] = 0.f;

    for (int jj0 = 0; jj0 < 64; jj0++) {
        int jbg = jh * 64 + jj0;
        unsigned int word = mrow[rowl * 131 + jbg];
#pragma unroll
        for (int s = 0; s < 2; s++) {
            int j16 = jbg * 2 + s;
            unsigned int mb = (word >> (s * 16 + jsub)) & 0xffu;
            bf16x8 P[2];
#pragma unroll
            for (int hh = 0; hh < 2; hh++) {
                const float* ep = &e1[hh * 4096 + j16 * 16 + jsub];
                float4 E0 = *(const float4*)ep;
                float4 E4 = *(const float4*)(ep + 4);
                float ee[8] = {E0.x, E0.y, E0.z, E0.w, E4.x, E4.y, E4.z, E4.w};
                float pf[8];
#pragma unroll
                for (int jj = 0; jj < 8; jj++) {
                    // E2 = E1^0.01 via int-lerp pow trick (minor branch only)
                    unsigned int i2 = __umulhi(__float_as_uint(ee[jj]), 42949673u)
                                      + 1054699684u;
                    float m1 = ee[jj] * Ac[hh];
                    float m2 = __uint_as_float(i2) * Bc[hh];
                    float v = fmaxf(m1, m2);
                    pf[jj] = ((mb >> jj) & 1u) ? v : 0.f;
                    lacc[hh] += pf[jj];
                }
                union { unsigned int u[4]; bf16x8 v8; } pk;
#pragma unroll
                for (int i2p = 0; i2p < 4; i2p++)
                    pk.u[i2p] = __builtin_amdgcn_perm(__float_as_uint(pf[2 * i2p + 1]),
                                                      __float_as_uint(pf[2 * i2p]),
                                                      0x07060302u);
                P[hh] = pk.v8;
            }
            const bf16x8* bp = &HB32[(size_t)j16 * 512 + (ch * 4) * 64 + lane];
#pragma unroll
            for (int nt = 0; nt < 4; nt++) {
                bf16x8 bv = bp[nt * 64];
                acc[0][nt] = __builtin_amdgcn_mfma_f32_32x32x16_bf16(P[0], bv, acc[0][nt], 0, 0, 0);
                acc[1][nt] = __builtin_amdgcn_mfma_f32_32x32x16_bf16(P[1], bv, acc[1][nt], 0, 0, 0);
            }
        }
    }

    // row sums: lanes r and r+32 cover disjoint j-subranges of the same row
    lacc[0] += __shfl_xor(lacc[0], 32);
    lacc[1] += __shfl_xor(lacc[1], 32);
    if (ch == 0 && lane < 32) {
        l_all[jh][0][lane] = lacc[0];
        l_all[jh][1][lane] = lacc[1];
    }
    __syncthreads();  // l_all visible; loop-phase LDS dead
    if (t < 32) {
#pragma unroll
        for (int hh = 0; hh < 2; hh++) {
            float lt = l_all[0][hh][t] + l_all[1][hh][t];
            linv_l[hh][t] = (lt > 0.f) ? 1.f / lt : 0.f;  // isolated row -> 0
        }
    }
    __syncthreads();

    // epilogue: two per-head rounds, 32KB accbuf each
#pragma unroll
    for (int r = 0; r < 2; r++) {
        if (jh == 1) {
#pragma unroll
            for (int nt = 0; nt < 4; nt++) {
                float* dp = accbuf + (size_t)((ch * 4 + nt) * 16) * 64 + lane;
#pragma unroll
                for (int reg = 0; reg < 16; reg++) dp[reg * 64] = acc[r][nt][reg];
            }
        }
        __syncthreads();
        if (jh == 0) {
            int khead = k0 + r;
#pragma unroll
            for (int nt = 0; nt < 4; nt++) {
                const float* sp = accbuf + (size_t)((ch * 4 + nt) * 16) * 64 + lane;
                int c = (ch * 4 + nt) * 32 + (lane & 31);
#pragma unroll
                for (int reg = 0; reg < 16; reg++) {
                    int rowloc = (reg & 3) + 8 * (reg >> 2) + 4 * (lane >> 5);
                    float v = (acc[r][nt][reg] + sp[reg * 64]) * linv_l[r][rowloc];
                    int i = i0 + rowloc;
                    if (MODE == 1) {
                        v += h[(size_t)i * HH + c];
                        v = (v > 0.f) ? v : (__expf(v) - 1.f);  // elu
                        ((short*)outp)[(size_t)i * KH + (size_t)khead * HH + c] = f2bf(v);
                    } else {
                        ((short*)outp)[(size_t)khead * NN * HH + (size_t)i * HH + c] = f2bf(v);
                    }
                }
            }
        }
        if (r == 0) __syncthreads();
    }
}

// ---------------- elu(avg of heads) column partial sums (bf16 planes) --------
__global__ void colsum_kernel(const float* __restrict__ h2,
                              const short* __restrict__ heads,
                              float* __restrict__ partial) {
    int c = threadIdx.x;
    int b = blockIdx.x;
    float s = 0.f;
    for (int il = 0; il < 64; il++) {
        int i = b * 64 + il;
        float v = h2[(size_t)i * HH + c];
#pragma unroll
        for (int k = 0; k < KK; k++) {
            unsigned int bits = (unsigned int)(unsigned short)heads[(size_t)k * NN * HH + (size_t)i * HH + c];
            v += 0.125f * __uint_as_float(bits << 16);
        }
        s += (v > 0.f) ? v : (__expf(v) - 1.f);
    }
    partial[b * HH + c] = s;
}

__global__ void final_kernel(const float* __restrict__ partial,
                             const float* __restrict__ out_w,
                             const float* __restrict__ out_b,
                             float* __restrict__ dout) {
    __shared__ float red[256];
    int c = threadIdx.x;
    float s = 0.f;
    for (int b = 0; b < 64; b++) s += partial[b * HH + c];
    red[c] = (s / 4096.f) * out_w[c];
    __syncthreads();
    for (int off = 128; off > 0; off >>= 1) {
        if (c < off) red[c] += red[c + off];
        __syncthreads();
    }
    if (c == 0) dout[0] = red[0] + out_b[0];
}

extern "C" void kernel_launch(void* const* d_in, const int* in_sizes, int n_in,
                              void* d_out, int out_size, void* d_ws, size_t ws_size,
                              hipStream_t stream) {
    (void)in_sizes; (void)n_in; (void)out_size; (void)ws_size;
    const float* adj   = (const float*)d_in[0];
    const float* feats = (const float*)d_in[1];
    const float* W1_w  = (const float*)d_in[2];
    const float* W1_b  = (const float*)d_in[3];
    const float* a1_w  = (const float*)d_in[4];
    const float* a1_b  = (const float*)d_in[5];
    const float* W2_w  = (const float*)d_in[6];
    const float* W2_b  = (const float*)d_in[7];
    const float* a2_w  = (const float*)d_in[8];
    const float* a2_b  = (const float*)d_in[9];
    const float* out_w = (const float*)d_in[10];
    const float* out_b = (const float*)d_in[11];

    char* w = (char*)d_ws;
    const size_t MB = 1ull << 20;
    unsigned int* mbits = (unsigned int*)(w);              // 0..2MB
    bf16x8* Aadj   = (bf16x8*)(w + 2 * MB);                // 2..34MB   (phase 1)
    short*  h1nb   = (short*)(w + 2 * MB);                 // 2..18MB   (phase 2: attn1 out bf16)
    bf16x8* h1na   = (bf16x8*)(w + 18 * MB);               // 18..34MB  (phase 2: A-frag)
    short*  planes = (short*)(w + 2 * MB);                 // 2..18MB   (phase 3: head planes bf16)
    bf16x8* Bfeats = (bf16x8*)(w + 34 * MB);               // 34..38MB  (phase 1)
    float*  h2     = (float*)(w + 34 * MB);                // 34..38MB  (phase 3)
    float*  tmp1   = (float*)(w + 38 * MB);                // 38..46MB  (phase 1)
    float*  h1     = (float*)(w + 38 * MB);                // 38..42MB  (phase 2; tmp1 dead)
    bf16x8* W1f    = (bf16x8*)(w + 42 * MB);               // 256 KB
    bf16x8* W2f    = (bf16x8*)(w + 42 * MB + 256 * 1024);  // 1 MB
    float*  srcT   = (float*)(w + 43 * MB + 256 * 1024);   // 128 KB
    float*  dstT   = (float*)(w + 43 * MB + 384 * 1024);   // 128 KB
    float*  maxd   = (float*)(w + 43 * MB + 512 * 1024);   // tiny
    bf16x8* HB32   = (bf16x8*)(w + 44 * MB);               // 44..46MB (2 MB)
    bf16x8* tmp1a  = (bf16x8*)(w + 46 * MB);               // 46..50MB
    float*  partial = (float*)(w + 50 * MB);               // 64 KB

    // --- phase 1: h1 = (A @ feats) @ W1^T + b1 ---
    cvt_adj_kernel<<<NN / 16, 256, 0, stream>>>(adj, Aadj, mbits);
    cvt_b_frag_kernel<FF><<<NN / 32, 256, 0, stream>>>(feats, Bfeats);
    gemm_frag_kernel<<<dim3(FF / 128, NN / 64), 256, 0, stream>>>(
        Aadj, Bfeats, nullptr, tmp1, NN / 32, FF / 16, FF);
    cvt_a_frag_kernel<float><<<NN / 16, 256, 0, stream>>>(tmp1, tmp1a, FF);
    cvt_bt_frag_kernel<<<HH / 16, 256, 0, stream>>>(W1_w, W1f, FF, HH / 16);
    gemm_frag_kernel<<<dim3(HH / 128, NN / 64), 256, 0, stream>>>(
        tmp1a, W1f, W1_b, h1, FF / 32, HH / 16, HH);

    // --- phase 2: layer-1 attention -> h1nb (bf16), then h2 ---
    prep_kernel<<<NN / 32, 256, 0, stream>>>(h1, a1_w, a1_b, HB32, srcT, dstT);
    maxdst_kernel<<<KK, 256, 0, stream>>>(dstT, maxd);
    attn32_kernel<1><<<dim3(NN / 32, KK / 2), 256, 0, stream>>>(
        h1, srcT, dstT, maxd, mbits, HB32, h1nb);
    cvt_a_frag_kernel<short><<<NN / 16, 256, 0, stream>>>(h1nb, h1na, KH);
    cvt_bt_frag_kernel<<<HH / 16, 256, 0, stream>>>(W2_w, W2f, KH, HH / 16);
    gemm_frag_kernel<<<dim3(HH / 128, NN / 64), 256, 0, stream>>>(
        h1na, W2f, W2_b, h2, KH / 32, HH / 16, HH);

    // --- phase 3: layer-2 attention -> bf16 head planes, reduce ---
    prep_kernel<<<NN / 32, 256, 0, stream>>>(h2, a2_w, a2_b, HB32, srcT, dstT);
    maxdst_kernel<<<KK, 256, 0, stream>>>(dstT, maxd);
    attn32_kernel<2><<<dim3(NN / 32, KK / 2), 256, 0, stream>>>(
        h2, srcT, dstT, maxd, mbits, HB32, planes);
    colsum_kernel<<<64, 256, 0, stream>>>(h2, planes, partial);
    final_kernel<<<1, 256, 0, stream>>>(partial, out_w, out_b, (float*)d_out);
}

// Round 6
// 542.403 us; speedup vs baseline: 1.3983x; 1.3983x over previous
//
#include <hip/hip_runtime.h>
#include <hip/hip_bf16.h>

// GAT round 5: fix R4 regression. attn: launch_bounds(256,2) (no spill), E1/E2
// bf16 LDS tables (no transcendental & no quarter-rate op in hot loop),
// 49KB loop LDS -> 3 blocks/CU. maxdst folded into prep via atomicMax.

#define NN 4096
#define FF 512
#define HH 256
#define KK 8
#define KH 2048  // KK*HH

typedef __attribute__((ext_vector_type(8))) short bf16x8;
typedef __attribute__((ext_vector_type(4))) float f32x4;
typedef __attribute__((ext_vector_type(16))) float f32x16;

__device__ inline short f2bf(float x) {
    __hip_bfloat16 b = __float2bfloat16(x);
    return *reinterpret_cast<short*>(&b);
}
__device__ inline short to_bf(float x) { return f2bf(x); }
__device__ inline short to_bf(short x) { return x; }

// monotone float<->uint encoding for atomicMax
__device__ inline unsigned int enc_f(float x) {
    unsigned int u = __float_as_uint(x);
    return (u & 0x80000000u) ? ~u : (u | 0x80000000u);
}
__device__ inline float dec_f(unsigned int e) {
    unsigned int u = (e & 0x80000000u) ? (e ^ 0x80000000u) : ~e;
    return __uint_as_float(u);
}

// ---- adjacency: fp32 -> A-frag bf16 (exact) + mask bitpack, single 64MB read ----
__global__ __launch_bounds__(256) void cvt_adj_kernel(const float* __restrict__ adj,
                                                      bf16x8* __restrict__ Af,
                                                      unsigned int* __restrict__ mbits) {
    int t = threadIdx.x, lane = t & 63, w = t >> 6, mt = blockIdx.x;
    int m = mt * 16 + (lane & 15), kq = (lane >> 4) * 8;
    for (int kt = w; kt < 128; kt += 4) {
        size_t base = (size_t)m * NN + kt * 32 + kq;
        float4 f0 = *(const float4*)&adj[base];
        float4 f1 = *(const float4*)&adj[base + 4];
        bf16x8 v;
        v[0] = f2bf(f0.x); v[1] = f2bf(f0.y); v[2] = f2bf(f0.z); v[3] = f2bf(f0.w);
        v[4] = f2bf(f1.x); v[5] = f2bf(f1.y); v[6] = f2bf(f1.z); v[7] = f2bf(f1.w);
        Af[((size_t)mt * 128 + kt) * 64 + lane] = v;
    }
    for (int r = w; r < 16; r += 4) {
        int row = mt * 16 + r;
        for (int j0 = 0; j0 < NN; j0 += 64) {
            float vv = adj[(size_t)row * NN + j0 + lane];
            unsigned long long b = __ballot(vv == 1.0f);
            if (lane == 0) {
                mbits[row * 128 + (j0 >> 5)]     = (unsigned int)(b & 0xffffffffull);
                mbits[row * 128 + (j0 >> 5) + 1] = (unsigned int)(b >> 32);
            }
        }
    }
}

// ---- row-major [M][K] (fp32 or bf16 bits) -> A-frag bf16 (16x16x32 layout) ----
template <typename T>
__global__ __launch_bounds__(256) void cvt_a_frag_kernel(const T* __restrict__ src,
                                                         bf16x8* __restrict__ dst, int K) {
    int t = threadIdx.x, lane = t & 63, w = t >> 6, mt = blockIdx.x;
    int Kt = K >> 5;
    int m = mt * 16 + (lane & 15), kq = (lane >> 4) * 8;
    for (int kt = w; kt < Kt; kt += 4) {
        size_t base = (size_t)m * K + kt * 32 + kq;
        bf16x8 v;
#pragma unroll
        for (int jj = 0; jj < 8; jj++) v[jj] = to_bf(src[base + jj]);
        dst[((size_t)mt * Kt + kt) * 64 + lane] = v;
    }
}

// ---- W [N][K] row-major (B^T) fp32 -> B-frag bf16 ----
__global__ __launch_bounds__(256) void cvt_bt_frag_kernel(const float* __restrict__ Wm,
                                                          bf16x8* __restrict__ dst,
                                                          int K, int Nt) {
    int t = threadIdx.x, lane = t & 63, w = t >> 6, nt = blockIdx.x;
    int Kt = K >> 5;
    int n = nt * 16 + (lane & 15), kq = (lane >> 4) * 8;
    for (int kt = w; kt < Kt; kt += 4) {
        size_t base = (size_t)n * K + kt * 32 + kq;
        bf16x8 v;
#pragma unroll
        for (int jj = 0; jj < 8; jj++) v[jj] = f2bf(Wm[base + jj]);
        dst[((size_t)kt * Nt + nt) * 64 + lane] = v;
    }
}

// ---- src [K][W] fp32 -> B-frag bf16 (16x16x32 layout, LDS-staged) ----
template <int W>
__global__ __launch_bounds__(256) void cvt_b_frag_kernel(const float* __restrict__ src,
                                                         bf16x8* __restrict__ dst) {
    __shared__ float hs[32][W + 8];
    constexpr int Nt = W / 16;
    int t = threadIdx.x, jb = blockIdx.x;
    {
        int r = t >> 3, cb = (t & 7) * (W / 8);
        const float* sp = &src[(size_t)(jb * 32 + r) * W + cb];
#pragma unroll
        for (int q = 0; q < W / 32; q++) *(float4*)&hs[r][cb + q * 4] = *(const float4*)&sp[q * 4];
    }
    __syncthreads();
    for (int id = t; id < Nt * 64; id += 256) {
        int nt = id >> 6, lane = id & 63;
        int c = nt * 16 + (lane & 15), q8 = (lane >> 4) * 8;
        bf16x8 v;
#pragma unroll
        for (int jj = 0; jj < 8; jj++) v[jj] = f2bf(hs[q8 + jj][c]);
        dst[((size_t)jb * Nt + nt) * 64 + lane] = v;
    }
}

// ---- fragment-direct bf16 MFMA GEMM (16x16x32): C = A@B (+bias) ----
__global__ __launch_bounds__(256) void gemm_frag_kernel(
    const bf16x8* __restrict__ Af, const bf16x8* __restrict__ Bf,
    const float* __restrict__ bias, float* __restrict__ C,
    int Kt, int Nt, int Nrow) {
    int t = threadIdx.x, lane = t & 63, w = t >> 6;
    int quad = lane >> 4, c16 = lane & 15;
    int wm = w & 1, wn = w >> 1;
    int mt0 = blockIdx.y * 4 + wm * 2;
    int nt0 = blockIdx.x * 8 + wn * 4;
    f32x4 acc[2][4];
#pragma unroll
    for (int i = 0; i < 2; i++)
#pragma unroll
        for (int j = 0; j < 4; j++) acc[i][j] = (f32x4){0.f, 0.f, 0.f, 0.f};
    const bf16x8* ap = Af + (size_t)mt0 * Kt * 64 + lane;
    const bf16x8* bp = Bf + (size_t)nt0 * 64 + lane;
#pragma unroll 2
    for (int kt = 0; kt < Kt; kt++) {
        bf16x8 a0 = ap[(size_t)kt * 64];
        bf16x8 a1 = ap[((size_t)Kt + kt) * 64];
        bf16x8 b0 = bp[(size_t)kt * Nt * 64];
        bf16x8 b1 = bp[((size_t)kt * Nt + 1) * 64];
        bf16x8 b2 = bp[((size_t)kt * Nt + 2) * 64];
        bf16x8 b3 = bp[((size_t)kt * Nt + 3) * 64];
        acc[0][0] = __builtin_amdgcn_mfma_f32_16x16x32_bf16(a0, b0, acc[0][0], 0, 0, 0);
        acc[0][1] = __builtin_amdgcn_mfma_f32_16x16x32_bf16(a0, b1, acc[0][1], 0, 0, 0);
        acc[0][2] = __builtin_amdgcn_mfma_f32_16x16x32_bf16(a0, b2, acc[0][2], 0, 0, 0);
        acc[0][3] = __builtin_amdgcn_mfma_f32_16x16x32_bf16(a0, b3, acc[0][3], 0, 0, 0);
        acc[1][0] = __builtin_amdgcn_mfma_f32_16x16x32_bf16(a1, b0, acc[1][0], 0, 0, 0);
        acc[1][1] = __builtin_amdgcn_mfma_f32_16x16x32_bf16(a1, b1, acc[1][1], 0, 0, 0);
        acc[1][2] = __builtin_amdgcn_mfma_f32_16x16x32_bf16(a1, b2, acc[1][2], 0, 0, 0);
        acc[1][3] = __builtin_amdgcn_mfma_f32_16x16x32_bf16(a1, b3, acc[1][3], 0, 0, 0);
    }
#pragma unroll
    for (int i = 0; i < 2; i++) {
#pragma unroll
        for (int j = 0; j < 4; j++) {
            int n = (nt0 + j) * 16 + c16;
            float bv = bias ? bias[n] : 0.f;
#pragma unroll
            for (int reg = 0; reg < 4; reg++) {
                int m = (mt0 + i) * 16 + quad * 4 + reg;
                C[(size_t)m * Nrow + n] = acc[i][j][reg] + bv;
            }
        }
    }
}

// ---- prep: h -> HB32 (32x32x16 B-frag order) + srcT/dstT (log2e-scaled)
//      + per-head max(dst) via atomicMax (maxd_u must be memset-0 beforehand) ----
__global__ __launch_bounds__(256) void prep_kernel(const float* __restrict__ h,
                                                   const float* __restrict__ aw,
                                                   const float* __restrict__ ab,
                                                   bf16x8* __restrict__ HB32,
                                                   float* __restrict__ srcT,
                                                   float* __restrict__ dstT,
                                                   unsigned int* __restrict__ maxd_u) {
    __shared__ __align__(16) float hs[32][264];
    __shared__ __align__(16) float awl[KK * 512];
    int t = threadIdx.x, jb = blockIdx.x;
#pragma unroll
    for (int q = 0; q < 4; q++)
        *(float4*)&awl[(t + q * 256) * 4] = *(const float4*)&aw[(t + q * 256) * 4];
    {
        int r = t >> 3, cb = (t & 7) * 32;
        const float* hp = &h[(size_t)(jb * 32 + r) * HH + cb];
#pragma unroll
        for (int q = 0; q < 8; q++) *(float4*)&hs[r][cb + q * 4] = *(const float4*)&hp[q * 4];
    }
    __syncthreads();
#pragma unroll
    for (int it = 0; it < 4; it++) {
        int id = t + it * 256;
        int q = id >> 9, nt = (id >> 6) & 7, lane = id & 63;
        int c = nt * 32 + (lane & 31), j8 = q * 16 + (lane >> 5) * 8;
        bf16x8 v;
#pragma unroll
        for (int jj = 0; jj < 8; jj++) v[jj] = f2bf(hs[j8 + jj][c]);
        HB32[((size_t)(jb * 2 + q)) * 512 + nt * 64 + lane] = v;
    }
    {
        const float LOG2E = 1.4426950408889634f;
        int row = t & 31, head = t >> 5;
        float s = ab[head], d = 0.f;
        const float* ws = &awl[head * 512];
        const float* wd = ws + 256;
#pragma unroll 4
        for (int c = 0; c < 256; c += 4) {
            float4 hv = *(const float4*)&hs[row][c];
            float4 a4 = *(const float4*)&ws[c];
            float4 b4 = *(const float4*)&wd[c];
            s += hv.x * a4.x + hv.y * a4.y + hv.z * a4.z + hv.w * a4.w;
            d += hv.x * b4.x + hv.y * b4.y + hv.z * b4.z + hv.w * b4.w;
        }
        float ds = d * LOG2E;
        srcT[head * NN + jb * 32 + row] = s * LOG2E;
        dstT[head * NN + jb * 32 + row] = ds;
        // per-head max over this block's 32 rows, then one atomic
        float mx = ds;
#pragma unroll
        for (int off = 16; off > 0; off >>= 1) mx = fmaxf(mx, __shfl_xor(mx, off));
        if (row == 0) atomicMax(&maxd_u[head], enc_f(mx));
    }
}

// ---- attention, 32x32x16 MFMA: block = 32 rows x 2 heads, 4 waves -----------
// P-gen: p = max(E1_j*Ac_row, E2_j*Bc_row); E1=2^dd, E2=2^(0.01*dd) as bf16 LDS
// tables built once per block. No transcendental / quarter-rate op in hot loop.
template <int MODE>
__global__ __launch_bounds__(256, 2) void attn32_kernel(
    const float* __restrict__ h, const float* __restrict__ srcT,
    const float* __restrict__ dstT, const unsigned int* __restrict__ maxd_u,
    const unsigned int* __restrict__ mbits, const bf16x8* __restrict__ HB32,
    void* __restrict__ outp) {
    __shared__ __align__(16) char smraw[49600];
    __shared__ float l_all[2][2][32];
    __shared__ float linv_l[2][32];
    unsigned short* e1 = (unsigned short*)smraw;            // [2][4096] bf16 (loop)
    unsigned short* e2 = (unsigned short*)(smraw + 16384);  // [2][4096] bf16 (loop)
    unsigned int* mrow = (unsigned int*)(smraw + 32768);    // [32*131]       (loop)
    float* accbuf = (float*)smraw;                          // 32 KB          (epi)

    int t = threadIdx.x;
    int i0 = blockIdx.x * 32;
    int k0 = blockIdx.y * 2;

#pragma unroll
    for (int q = 0; q < 8; q++) {
        int idx = t + q * 256;                // 0..2047, 4 entries each
        int hh = idx >> 10, off = (idx & 1023) * 4;
        float4 dv = *(const float4*)&dstT[(size_t)(k0 + hh) * NN + off];
        float a0 = __builtin_amdgcn_exp2f(dv.x);
        float a1 = __builtin_amdgcn_exp2f(dv.y);
        float a2 = __builtin_amdgcn_exp2f(dv.z);
        float a3 = __builtin_amdgcn_exp2f(dv.w);
        float b0 = __builtin_amdgcn_exp2f(0.01f * dv.x);
        float b1 = __builtin_amdgcn_exp2f(0.01f * dv.y);
        float b2 = __builtin_amdgcn_exp2f(0.01f * dv.z);
        float b3 = __builtin_amdgcn_exp2f(0.01f * dv.w);
        uint2 p1, p2;
        p1.x = __builtin_amdgcn_perm(__float_as_uint(a1), __float_as_uint(a0), 0x07060302u);
        p1.y = __builtin_amdgcn_perm(__float_as_uint(a3), __float_as_uint(a2), 0x07060302u);
        p2.x = __builtin_amdgcn_perm(__float_as_uint(b1), __float_as_uint(b0), 0x07060302u);
        p2.y = __builtin_amdgcn_perm(__float_as_uint(b3), __float_as_uint(b2), 0x07060302u);
        *(uint2*)&e1[hh * 4096 + off] = p1;
        *(uint2*)&e2[hh * 4096 + off] = p2;
    }
#pragma unroll
    for (int q = 0; q < 16; q++) {
        int idx = t + q * 256;                // 0..4095
        int r = idx >> 7, wd = idx & 127;
        mrow[r * 131 + wd] = mbits[(size_t)(i0 + r) * 128 + wd];
    }
    __syncthreads();

    int lane = t & 63, w = t >> 6;
    int jh = w & 1, ch = w >> 1;
    int rowl = lane & 31, jsub = (lane >> 5) * 8;

    float Ac[2], Bc[2], lacc[2] = {0.f, 0.f};
#pragma unroll
    for (int hh = 0; hh < 2; hh++) {
        float sL = srcT[(size_t)(k0 + hh) * NN + i0 + rowl];
        float xm = sL + dec_f(maxd_u[k0 + hh]);
        float mL = fmaxf(xm, 0.01f * xm);     // lrelu upper bound (log2 domain)
        Ac[hh] = __builtin_amdgcn_exp2f(sL - mL);
        Bc[hh] = __builtin_amdgcn_exp2f(fmaf(0.01f, sL, -mL));
    }

    f32x16 acc[2][4];
#pragma unroll
    for (int hh = 0; hh < 2; hh++)
#pragma unroll
        for (int nt = 0; nt < 4; nt++)
#pragma unroll
            for (int r = 0; r < 16; r++) acc[hh][nt][r] = 0.f;

    for (int jj0 = 0; jj0 < 64; jj0++) {
        int jbg = jh * 64 + jj0;
        unsigned int word = mrow[rowl * 131 + jbg];
#pragma unroll
        for (int s = 0; s < 2; s++) {
            int j16 = jbg * 2 + s;
            unsigned int mb = (word >> (s * 16 + jsub)) & 0xffu;
            bf16x8 P[2];
#pragma unroll
            for (int hh = 0; hh < 2; hh++) {
                union { bf16x8 v; unsigned int u[4]; } U1, U2;
                U1.v = *(const bf16x8*)&e1[hh * 4096 + j16 * 16 + jsub];
                U2.v = *(const bf16x8*)&e2[hh * 4096 + j16 * 16 + jsub];
                float pf[8];
#pragma unroll
                for (int jp = 0; jp < 4; jp++) {
                    float e1lo = __uint_as_float(U1.u[jp] << 16);
                    float e1hi = __uint_as_float(U1.u[jp] & 0xffff0000u);
                    float e2lo = __uint_as_float(U2.u[jp] << 16);
                    float e2hi = __uint_as_float(U2.u[jp] & 0xffff0000u);
                    float vlo = fmaxf(e1lo * Ac[hh], e2lo * Bc[hh]);
                    float vhi = fmaxf(e1hi * Ac[hh], e2hi * Bc[hh]);
                    pf[2 * jp]     = ((mb >> (2 * jp)) & 1u) ? vlo : 0.f;
                    pf[2 * jp + 1] = ((mb >> (2 * jp + 1)) & 1u) ? vhi : 0.f;
                    lacc[hh] += pf[2 * jp] + pf[2 * jp + 1];
                }
                union { unsigned int u[4]; bf16x8 v8; } pk;
#pragma unroll
                for (int i2p = 0; i2p < 4; i2p++)
                    pk.u[i2p] = __builtin_amdgcn_perm(__float_as_uint(pf[2 * i2p + 1]),
                                                      __float_as_uint(pf[2 * i2p]),
                                                      0x07060302u);
                P[hh] = pk.v8;
            }
            const bf16x8* bp = &HB32[(size_t)j16 * 512 + (ch * 4) * 64 + lane];
#pragma unroll
            for (int nt = 0; nt < 4; nt++) {
                bf16x8 bv = bp[nt * 64];
                acc[0][nt] = __builtin_amdgcn_mfma_f32_32x32x16_bf16(P[0], bv, acc[0][nt], 0, 0, 0);
                acc[1][nt] = __builtin_amdgcn_mfma_f32_32x32x16_bf16(P[1], bv, acc[1][nt], 0, 0, 0);
            }
        }
    }

    // row sums: lanes r and r+32 cover disjoint j-subranges of the same row
    lacc[0] += __shfl_xor(lacc[0], 32);
    lacc[1] += __shfl_xor(lacc[1], 32);
    if (ch == 0 && lane < 32) {
        l_all[jh][0][lane] = lacc[0];
        l_all[jh][1][lane] = lacc[1];
    }
    __syncthreads();  // l_all visible; loop-phase LDS dead
    if (t < 32) {
#pragma unroll
        for (int hh = 0; hh < 2; hh++) {
            float lt = l_all[0][hh][t] + l_all[1][hh][t];
            linv_l[hh][t] = (lt > 0.f) ? 1.f / lt : 0.f;  // isolated row -> 0
        }
    }
    __syncthreads();

    // epilogue: two per-head rounds, 32KB accbuf each
#pragma unroll
    for (int r = 0; r < 2; r++) {
        if (jh == 1) {
#pragma unroll
            for (int nt = 0; nt < 4; nt++) {
                float* dp = accbuf + (size_t)((ch * 4 + nt) * 16) * 64 + lane;
#pragma unroll
                for (int reg = 0; reg < 16; reg++) dp[reg * 64] = acc[r][nt][reg];
            }
        }
        __syncthreads();
        if (jh == 0) {
            int khead = k0 + r;
#pragma unroll
            for (int nt = 0; nt < 4; nt++) {
                const float* sp = accbuf + (size_t)((ch * 4 + nt) * 16) * 64 + lane;
                int c = (ch * 4 + nt) * 32 + (lane & 31);
#pragma unroll
                for (int reg = 0; reg < 16; reg++) {
                    int rowloc = (reg & 3) + 8 * (reg >> 2) + 4 * (lane >> 5);
                    float v = (acc[r][nt][reg] + sp[reg * 64]) * linv_l[r][rowloc];
                    int i = i0 + rowloc;
                    if (MODE == 1) {
                        v += h[(size_t)i * HH + c];
                        v = (v > 0.f) ? v : (__expf(v) - 1.f);  // elu
                        ((short*)outp)[(size_t)i * KH + (size_t)khead * HH + c] = f2bf(v);
                    } else {
                        ((short*)outp)[(size_t)khead * NN * HH + (size_t)i * HH + c] = f2bf(v);
                    }
                }
            }
        }
        if (r == 0) __syncthreads();
    }
}

// ---------------- elu(avg of heads) column partial sums (bf16 planes) --------
__global__ void colsum_kernel(const float* __restrict__ h2,
                              const short* __restrict__ heads,
                              float* __restrict__ partial) {
    int c = threadIdx.x;
    int b = blockIdx.x;
    float s = 0.f;
    for (int il = 0; il < 64; il++) {
        int i = b * 64 + il;
        float v = h2[(size_t)i * HH + c];
#pragma unroll
        for (int k = 0; k < KK; k++) {
            unsigned int bits = (unsigned int)(unsigned short)heads[(size_t)k * NN * HH + (size_t)i * HH + c];
            v += 0.125f * __uint_as_float(bits << 16);
        }
        s += (v > 0.f) ? v : (__expf(v) - 1.f);
    }
    partial[b * HH + c] = s;
}

__global__ void final_kernel(const float* __restrict__ partial,
                             const float* __restrict__ out_w,
                             const float* __restrict__ out_b,
                             float* __restrict__ dout) {
    __shared__ float red[256];
    int c = threadIdx.x;
    float s = 0.f;
    for (int b = 0; b < 64; b++) s += partial[b * HH + c];
    red[c] = (s / 4096.f) * out_w[c];
    __syncthreads();
    for (int off = 128; off > 0; off >>= 1) {
        if (c < off) red[c] += red[c + off];
        __syncthreads();
    }
    if (c == 0) dout[0] = red[0] + out_b[0];
}

extern "C" void kernel_launch(void* const* d_in, const int* in_sizes, int n_in,
                              void* d_out, int out_size, void* d_ws, size_t ws_size,
                              hipStream_t stream) {
    (void)in_sizes; (void)n_in; (void)out_size; (void)ws_size;
    const float* adj   = (const float*)d_in[0];
    const float* feats = (const float*)d_in[1];
    const float* W1_w  = (const float*)d_in[2];
    const float* W1_b  = (const float*)d_in[3];
    const float* a1_w  = (const float*)d_in[4];
    const float* a1_b  = (const float*)d_in[5];
    const float* W2_w  = (const float*)d_in[6];
    const float* W2_b  = (const float*)d_in[7];
    const float* a2_w  = (const float*)d_in[8];
    const float* a2_b  = (const float*)d_in[9];
    const float* out_w = (const float*)d_in[10];
    const float* out_b = (const float*)d_in[11];

    char* w = (char*)d_ws;
    const size_t MB = 1ull << 20;
    unsigned int* mbits = (unsigned int*)(w);              // 0..2MB
    bf16x8* Aadj   = (bf16x8*)(w + 2 * MB);                // 2..34MB   (phase 1)
    short*  h1nb   = (short*)(w + 2 * MB);                 // 2..18MB   (phase 2: attn1 out bf16)
    bf16x8* h1na   = (bf16x8*)(w + 18 * MB);               // 18..34MB  (phase 2: A-frag)
    short*  planes = (short*)(w + 2 * MB);                 // 2..18MB   (phase 3: head planes bf16)
    bf16x8* Bfeats = (bf16x8*)(w + 34 * MB);               // 34..38MB  (phase 1)
    float*  h2     = (float*)(w + 34 * MB);                // 34..38MB  (phase 3)
    float*  tmp1   = (float*)(w + 38 * MB);                // 38..46MB  (phase 1)
    float*  h1     = (float*)(w + 38 * MB);                // 38..42MB  (phase 2; tmp1 dead)
    bf16x8* W1f    = (bf16x8*)(w + 42 * MB);               // 256 KB
    bf16x8* W2f    = (bf16x8*)(w + 42 * MB + 256 * 1024);  // 1 MB
    float*  srcT   = (float*)(w + 43 * MB + 256 * 1024);   // 128 KB
    float*  dstT   = (float*)(w + 43 * MB + 384 * 1024);   // 128 KB
    unsigned int* maxd_u = (unsigned int*)(w + 43 * MB + 512 * 1024);  // 32 B
    bf16x8* HB32   = (bf16x8*)(w + 44 * MB);               // 44..46MB (2 MB)
    bf16x8* tmp1a  = (bf16x8*)(w + 46 * MB);               // 46..50MB
    float*  partial = (float*)(w + 50 * MB);               // 64 KB

    // --- phase 1: h1 = (A @ feats) @ W1^T + b1 ---
    cvt_adj_kernel<<<NN / 16, 256, 0, stream>>>(adj, Aadj, mbits);
    cvt_b_frag_kernel<FF><<<NN / 32, 256, 0, stream>>>(feats, Bfeats);
    gemm_frag_kernel<<<dim3(FF / 128, NN / 64), 256, 0, stream>>>(
        Aadj, Bfeats, nullptr, tmp1, NN / 32, FF / 16, FF);
    cvt_a_frag_kernel<float><<<NN / 16, 256, 0, stream>>>(tmp1, tmp1a, FF);
    cvt_bt_frag_kernel<<<HH / 16, 256, 0, stream>>>(W1_w, W1f, FF, HH / 16);
    gemm_frag_kernel<<<dim3(HH / 128, NN / 64), 256, 0, stream>>>(
        tmp1a, W1f, W1_b, h1, FF / 32, HH / 16, HH);

    // --- phase 2: layer-1 attention -> h1nb (bf16), then h2 ---
    hipMemsetAsync(maxd_u, 0, KK * sizeof(unsigned int), stream);
    prep_kernel<<<NN / 32, 256, 0, stream>>>(h1, a1_w, a1_b, HB32, srcT, dstT, maxd_u);
    attn32_kernel<1><<<dim3(NN / 32, KK / 2), 256, 0, stream>>>(
        h1, srcT, dstT, maxd_u, mbits, HB32, h1nb);
    cvt_a_frag_kernel<short><<<NN / 16, 256, 0, stream>>>(h1nb, h1na, KH);
    cvt_bt_frag_kernel<<<HH / 16, 256, 0, stream>>>(W2_w, W2f, KH, HH / 16);
    gemm_frag_kernel<<<dim3(HH / 128, NN / 64), 256, 0, stream>>>(
        h1na, W2f, W2_b, h2, KH / 32, HH / 16, HH);

    // --- phase 3: layer-2 attention -> bf16 head planes, reduce ---
    hipMemsetAsync(maxd_u, 0, KK * sizeof(unsigned int), stream);
    prep_kernel<<<NN / 32, 256, 0, stream>>>(h2, a2_w, a2_b, HB32, srcT, dstT, maxd_u);
    attn32_kernel<2><<<dim3(NN / 32, KK / 2), 256, 0, stream>>>(
        h2, srcT, dstT, maxd_u, mbits, HB32, planes);
    colsum_kernel<<<64, 256, 0, stream>>>(h2, planes, partial);
    final_kernel<<<1, 256, 0, stream>>>(partial, out_w, out_b, (float*)d_out);
}

// Round 9
// 462.830 us; speedup vs baseline: 1.6387x; 1.1719x over previous
//
#include <hip/hip_runtime.h>
#include <hip/hip_bf16.h>
#include <hip/hip_fp16.h>

// GAT round 8: round 7 with the cvt_pkrtz return-type fixed (auto + memcpy;
// clang's builtin returns __fp16 vec, not _Float16 vec). attention P-gen in
// packed f16 (pk_mul/pk_max/dot2, mask via mul24 bit-spread), MFMA 32x32x16_f16.
// gemm1 expands A-fragments from mask bits in-register (no Aadj array).

#define NN 4096
#define FF 512
#define HH 256
#define KK 8
#define KH 2048  // KK*HH

typedef __attribute__((ext_vector_type(8))) short bf16x8;
typedef __attribute__((ext_vector_type(4))) float f32x4;
typedef __attribute__((ext_vector_type(16))) float f32x16;
typedef _Float16 h16x2 __attribute__((ext_vector_type(2)));
typedef _Float16 h16x8 __attribute__((ext_vector_type(8)));

__device__ inline short f2bf(float x) {
    __hip_bfloat16 b = __float2bfloat16(x);
    return *reinterpret_cast<short*>(&b);
}
__device__ inline short to_bf(float x) { return f2bf(x); }
__device__ inline short to_bf(short x) { return x; }

__device__ inline unsigned int pkh(float a, float b) {
    auto r = __builtin_amdgcn_cvt_pkrtz(a, b);  // __fp16 ext_vector(2)
    unsigned int u;
    __builtin_memcpy(&u, &r, 4);
    return u;
}
// packed-f16 mul/max on raw uint bit-bags (native _Float16 vector ops)
__device__ inline unsigned int h2mul(unsigned int a, unsigned int b) {
    h16x2 av, bv;
    __builtin_memcpy(&av, &a, 4);
    __builtin_memcpy(&bv, &b, 4);
    h16x2 r = av * bv;
    unsigned int u;
    __builtin_memcpy(&u, &r, 4);
    return u;
}
__device__ inline unsigned int h2max(unsigned int a, unsigned int b) {
    h16x2 av, bv;
    __builtin_memcpy(&av, &a, 4);
    __builtin_memcpy(&bv, &b, 4);
    h16x2 r = __builtin_elementwise_max(av, bv);
    unsigned int u;
    __builtin_memcpy(&u, &r, 4);
    return u;
}
__device__ inline float h2dot1(unsigned int a, float c) {
    h16x2 av;
    __builtin_memcpy(&av, &a, 4);
    h16x2 one = {(_Float16)1.0f, (_Float16)1.0f};
    return __builtin_amdgcn_fdot2(av, one, c, false);
}

// monotone float<->uint encoding for atomicMax
__device__ inline unsigned int enc_f(float x) {
    unsigned int u = __float_as_uint(x);
    return (u & 0x80000000u) ? ~u : (u | 0x80000000u);
}
__device__ inline float dec_f(unsigned int e) {
    unsigned int u = (e & 0x80000000u) ? (e ^ 0x80000000u) : ~e;
    return __uint_as_float(u);
}

// ---- mask pack: adjacency fp32 -> bitmask (2 MB); only adjacency reader ----
__global__ void pack_mask_kernel(const float* __restrict__ adj,
                                 unsigned int* __restrict__ mbits) {
    int i = blockIdx.x;
    int lane = threadIdx.x & 63;
    int wv = threadIdx.x >> 6;
    for (int j0 = wv * 64; j0 < NN; j0 += 256) {
        float v = adj[(size_t)i * NN + j0 + lane];
        unsigned long long b = __ballot(v == 1.0f);
        if (lane == 0) {
            mbits[i * 128 + (j0 >> 5)]     = (unsigned int)(b & 0xffffffffull);
            mbits[i * 128 + (j0 >> 5) + 1] = (unsigned int)(b >> 32);
        }
    }
}

// ---- row-major [M][K] (fp32 or bf16 bits) -> A-frag bf16 (16x16x32 layout) ----
template <typename T>
__global__ __launch_bounds__(256) void cvt_a_frag_kernel(const T* __restrict__ src,
                                                         bf16x8* __restrict__ dst, int K) {
    int t = threadIdx.x, lane = t & 63, w = t >> 6, mt = blockIdx.x;
    int Kt = K >> 5;
    int m = mt * 16 + (lane & 15), kq = (lane >> 4) * 8;
    for (int kt = w; kt < Kt; kt += 4) {
        size_t base = (size_t)m * K + kt * 32 + kq;
        bf16x8 v;
#pragma unroll
        for (int jj = 0; jj < 8; jj++) v[jj] = to_bf(src[base + jj]);
        dst[((size_t)mt * Kt + kt) * 64 + lane] = v;
    }
}

// ---- W [N][K] row-major (B^T) fp32 -> B-frag bf16 ----
__global__ __launch_bounds__(256) void cvt_bt_frag_kernel(const float* __restrict__ Wm,
                                                          bf16x8* __restrict__ dst,
                                                          int K, int Nt) {
    int t = threadIdx.x, lane = t & 63, w = t >> 6, nt = blockIdx.x;
    int Kt = K >> 5;
    int n = nt * 16 + (lane & 15), kq = (lane >> 4) * 8;
    for (int kt = w; kt < Kt; kt += 4) {
        size_t base = (size_t)n * K + kt * 32 + kq;
        bf16x8 v;
#pragma unroll
        for (int jj = 0; jj < 8; jj++) v[jj] = f2bf(Wm[base + jj]);
        dst[((size_t)kt * Nt + nt) * 64 + lane] = v;
    }
}

// ---- src [K][W] fp32 -> B-frag bf16 (16x16x32 layout, LDS-staged) ----
template <int W>
__global__ __launch_bounds__(256) void cvt_b_frag_kernel(const float* __restrict__ src,
                                                         bf16x8* __restrict__ dst) {
    __shared__ float hs[32][W + 8];
    constexpr int Nt = W / 16;
    int t = threadIdx.x, jb = blockIdx.x;
    {
        int r = t >> 3, cb = (t & 7) * (W / 8);
        const float* sp = &src[(size_t)(jb * 32 + r) * W + cb];
#pragma unroll
        for (int q = 0; q < W / 32; q++) *(float4*)&hs[r][cb + q * 4] = *(const float4*)&sp[q * 4];
    }
    __syncthreads();
    for (int id = t; id < Nt * 64; id += 256) {
        int nt = id >> 6, lane = id & 63;
        int c = nt * 16 + (lane & 15), q8 = (lane >> 4) * 8;
        bf16x8 v;
#pragma unroll
        for (int jj = 0; jj < 8; jj++) v[jj] = f2bf(hs[q8 + jj][c]);
        dst[((size_t)jb * Nt + nt) * 64 + lane] = v;
    }
}

// ---- fragment-direct bf16 MFMA GEMM (16x16x32): C = A@B (+bias) ----
__global__ __launch_bounds__(256) void gemm_frag_kernel(
    const bf16x8* __restrict__ Af, const bf16x8* __restrict__ Bf,
    const float* __restrict__ bias, float* __restrict__ C,
    int Kt, int Nt, int Nrow) {
    int t = threadIdx.x, lane = t & 63, w = t >> 6;
    int quad = lane >> 4, c16 = lane & 15;
    int wm = w & 1, wn = w >> 1;
    int mt0 = blockIdx.y * 4 + wm * 2;
    int nt0 = blockIdx.x * 8 + wn * 4;
    f32x4 acc[2][4];
#pragma unroll
    for (int i = 0; i < 2; i++)
#pragma unroll
        for (int j = 0; j < 4; j++) acc[i][j] = (f32x4){0.f, 0.f, 0.f, 0.f};
    const bf16x8* ap = Af + (size_t)mt0 * Kt * 64 + lane;
    const bf16x8* bp = Bf + (size_t)nt0 * 64 + lane;
#pragma unroll 2
    for (int kt = 0; kt < Kt; kt++) {
        bf16x8 a0 = ap[(size_t)kt * 64];
        bf16x8 a1 = ap[((size_t)Kt + kt) * 64];
        bf16x8 b0 = bp[(size_t)kt * Nt * 64];
        bf16x8 b1 = bp[((size_t)kt * Nt + 1) * 64];
        bf16x8 b2 = bp[((size_t)kt * Nt + 2) * 64];
        bf16x8 b3 = bp[((size_t)kt * Nt + 3) * 64];
        acc[0][0] = __builtin_amdgcn_mfma_f32_16x16x32_bf16(a0, b0, acc[0][0], 0, 0, 0);
        acc[0][1] = __builtin_amdgcn_mfma_f32_16x16x32_bf16(a0, b1, acc[0][1], 0, 0, 0);
        acc[0][2] = __builtin_amdgcn_mfma_f32_16x16x32_bf16(a0, b2, acc[0][2], 0, 0, 0);
        acc[0][3] = __builtin_amdgcn_mfma_f32_16x16x32_bf16(a0, b3, acc[0][3], 0, 0, 0);
        acc[1][0] = __builtin_amdgcn_mfma_f32_16x16x32_bf16(a1, b0, acc[1][0], 0, 0, 0);
        acc[1][1] = __builtin_amdgcn_mfma_f32_16x16x32_bf16(a1, b1, acc[1][1], 0, 0, 0);
        acc[1][2] = __builtin_amdgcn_mfma_f32_16x16x32_bf16(a1, b2, acc[1][2], 0, 0, 0);
        acc[1][3] = __builtin_amdgcn_mfma_f32_16x16x32_bf16(a1, b3, acc[1][3], 0, 0, 0);
    }
#pragma unroll
    for (int i = 0; i < 2; i++) {
#pragma unroll
        for (int j = 0; j < 4; j++) {
            int n = (nt0 + j) * 16 + c16;
            float bv = bias ? bias[n] : 0.f;
#pragma unroll
            for (int reg = 0; reg < 4; reg++) {
                int m = (mt0 + i) * 16 + quad * 4 + reg;
                C[(size_t)m * Nrow + n] = acc[i][j][reg] + bv;
            }
        }
    }
}

// ---- gemm1: C = adj @ B, A-fragments expanded from mbits in-register ----
__global__ __launch_bounds__(256) void gemm_adj_kernel(
    const unsigned int* __restrict__ mbits, const bf16x8* __restrict__ Bf,
    float* __restrict__ C, int Kt, int Nt, int Nrow) {
    int t = threadIdx.x, lane = t & 63, w = t >> 6;
    int quad = lane >> 4, c16 = lane & 15;
    int wm = w & 1, wn = w >> 1;
    int mt0 = blockIdx.y * 4 + wm * 2;
    int nt0 = blockIdx.x * 8 + wn * 4;
    int m = lane & 15, q8 = (lane >> 4) * 8;
    int row0 = mt0 * 16 + m, row1 = row0 + 16;
    f32x4 acc[2][4];
#pragma unroll
    for (int i = 0; i < 2; i++)
#pragma unroll
        for (int j = 0; j < 4; j++) acc[i][j] = (f32x4){0.f, 0.f, 0.f, 0.f};
    const bf16x8* bp = Bf + (size_t)nt0 * 64 + lane;
#pragma unroll 2
    for (int kt = 0; kt < Kt; kt++) {
        unsigned int w0 = mbits[(size_t)row0 * 128 + kt];
        unsigned int w1 = mbits[(size_t)row1 * 128 + kt];
        unsigned int mb0 = (w0 >> q8) & 0xffu;
        unsigned int mb1 = (w1 >> q8) & 0xffu;
        union { unsigned int u[4]; bf16x8 v; } A0, A1;
#pragma unroll
        for (int jp = 0; jp < 4; jp++) {
            unsigned int u0 = (mb0 >> (2 * jp)) & 3u;
            unsigned int u1 = (mb1 >> (2 * jp)) & 3u;
            A0.u[jp] = ((u0 * 0x8001u) & 0x10001u) * 0x3F80u;  // bf16 1.0 pair
            A1.u[jp] = ((u1 * 0x8001u) & 0x10001u) * 0x3F80u;
        }
        bf16x8 b0 = bp[(size_t)kt * Nt * 64];
        bf16x8 b1 = bp[((size_t)kt * Nt + 1) * 64];
        bf16x8 b2 = bp[((size_t)kt * Nt + 2) * 64];
        bf16x8 b3 = bp[((size_t)kt * Nt + 3) * 64];
        acc[0][0] = __builtin_amdgcn_mfma_f32_16x16x32_bf16(A0.v, b0, acc[0][0], 0, 0, 0);
        acc[0][1] = __builtin_amdgcn_mfma_f32_16x16x32_bf16(A0.v, b1, acc[0][1], 0, 0, 0);
        acc[0][2] = __builtin_amdgcn_mfma_f32_16x16x32_bf16(A0.v, b2, acc[0][2], 0, 0, 0);
        acc[0][3] = __builtin_amdgcn_mfma_f32_16x16x32_bf16(A0.v, b3, acc[0][3], 0, 0, 0);
        acc[1][0] = __builtin_amdgcn_mfma_f32_16x16x32_bf16(A1.v, b0, acc[1][0], 0, 0, 0);
        acc[1][1] = __builtin_amdgcn_mfma_f32_16x16x32_bf16(A1.v, b1, acc[1][1], 0, 0, 0);
        acc[1][2] = __builtin_amdgcn_mfma_f32_16x16x32_bf16(A1.v, b2, acc[1][2], 0, 0, 0);
        acc[1][3] = __builtin_amdgcn_mfma_f32_16x16x32_bf16(A1.v, b3, acc[1][3], 0, 0, 0);
    }
#pragma unroll
    for (int i = 0; i < 2; i++) {
#pragma unroll
        for (int j = 0; j < 4; j++) {
            int n = (nt0 + j) * 16 + c16;
#pragma unroll
            for (int reg = 0; reg < 4; reg++) {
                int mm = (mt0 + i) * 16 + quad * 4 + reg;
                C[(size_t)mm * Nrow + n] = acc[i][j][reg];
            }
        }
    }
}

// ---- prep: h -> HB16 (32x32x16 f16 B-frag) + srcT/dstT (log2e) + maxdst ----
__global__ __launch_bounds__(256) void prep_kernel(const float* __restrict__ h,
                                                   const float* __restrict__ aw,
                                                   const float* __restrict__ ab,
                                                   h16x8* __restrict__ HB16,
                                                   float* __restrict__ srcT,
                                                   float* __restrict__ dstT,
                                                   unsigned int* __restrict__ maxd_u) {
    __shared__ __align__(16) float hs[32][264];
    __shared__ __align__(16) float awl[KK * 512];
    int t = threadIdx.x, jb = blockIdx.x;
#pragma unroll
    for (int q = 0; q < 4; q++)
        *(float4*)&awl[(t + q * 256) * 4] = *(const float4*)&aw[(t + q * 256) * 4];
    {
        int r = t >> 3, cb = (t & 7) * 32;
        const float* hp = &h[(size_t)(jb * 32 + r) * HH + cb];
#pragma unroll
        for (int q = 0; q < 8; q++) *(float4*)&hs[r][cb + q * 4] = *(const float4*)&hp[q * 4];
    }
    __syncthreads();
#pragma unroll
    for (int it = 0; it < 4; it++) {
        int id = t + it * 256;
        int q = id >> 9, nt = (id >> 6) & 7, lane = id & 63;
        int c = nt * 32 + (lane & 31), j8 = q * 16 + (lane >> 5) * 8;
        union { unsigned int u[4]; h16x8 v; } pk;
#pragma unroll
        for (int jp = 0; jp < 4; jp++)
            pk.u[jp] = pkh(hs[j8 + 2 * jp][c], hs[j8 + 2 * jp + 1][c]);
        HB16[((size_t)(jb * 2 + q)) * 512 + nt * 64 + lane] = pk.v;
    }
    {
        const float LOG2E = 1.4426950408889634f;
        int row = t & 31, head = t >> 5;
        float s = ab[head], d = 0.f;
        const float* ws = &awl[head * 512];
        const float* wd = ws + 256;
#pragma unroll 4
        for (int c = 0; c < 256; c += 4) {
            float4 hv = *(const float4*)&hs[row][c];
            float4 a4 = *(const float4*)&ws[c];
            float4 b4 = *(const float4*)&wd[c];
            s += hv.x * a4.x + hv.y * a4.y + hv.z * a4.z + hv.w * a4.w;
            d += hv.x * b4.x + hv.y * b4.y + hv.z * b4.z + hv.w * b4.w;
        }
        float ds = d * LOG2E;
        srcT[head * NN + jb * 32 + row] = s * LOG2E;
        dstT[head * NN + jb * 32 + row] = ds;
        float mx = ds;
#pragma unroll
        for (int off = 16; off > 0; off >>= 1) mx = fmaxf(mx, __shfl_xor(mx, off));
        if (row == 0) atomicMax(&maxd_u[head], enc_f(mx));
    }
}

// ---- attention, 32x32x16 f16 MFMA: block = 32 rows x 2 heads, 4 waves -------
// p = max(E1_j*Ac_i, E2_j*Bc_i) with E1=2^(d-D), E2=2^(0.01(d-D)) packed-f16
// LDS tables; Ac=2^(s+D-m), Bc=2^(0.01(s+D)-m), m=lrelu(s+D). Mask applied by
// AND with mul24 bit-spread words. l-sums via v_dot2 f32. No transcendental,
// no scalar f32 math, no pack step in the hot loop.
template <int MODE>
__global__ __launch_bounds__(256, 2) void attn32_kernel(
    const float* __restrict__ h, const float* __restrict__ srcT,
    const float* __restrict__ dstT, const unsigned int* __restrict__ maxd_u,
    const unsigned int* __restrict__ mbits, const h16x8* __restrict__ HB16,
    void* __restrict__ outp) {
    __shared__ __align__(16) char smraw[49600];
    __shared__ float l_all[2][2][32];
    __shared__ float linv_l[2][32];
    unsigned short* e1t = (unsigned short*)smraw;            // [2][4096] f16 (loop)
    unsigned short* e2t = (unsigned short*)(smraw + 16384);  // [2][4096] f16 (loop)
    unsigned int* mrow = (unsigned int*)(smraw + 32768);     // [32*131]      (loop)
    float* accbuf = (float*)smraw;                           // 32 KB         (epi)

    int t = threadIdx.x;
    int i0 = blockIdx.x * 32;
    int k0 = blockIdx.y * 2;

    float Dv0 = dec_f(maxd_u[k0]), Dv1 = dec_f(maxd_u[k0 + 1]);
#pragma unroll
    for (int q = 0; q < 8; q++) {
        int idx = t + q * 256;                // 0..2047, 4 entries each
        int hh = idx >> 10, off = (idx & 1023) * 4;
        float D = hh ? Dv1 : Dv0;
        float4 dv = *(const float4*)&dstT[(size_t)(k0 + hh) * NN + off];
        float d0 = dv.x - D, d1 = dv.y - D, d2 = dv.z - D, d3 = dv.w - D;
        uint2 p1, p2;
        p1.x = pkh(__builtin_amdgcn_exp2f(d0), __builtin_amdgcn_exp2f(d1));
        p1.y = pkh(__builtin_amdgcn_exp2f(d2), __builtin_amdgcn_exp2f(d3));
        p2.x = pkh(__builtin_amdgcn_exp2f(0.01f * d0), __builtin_amdgcn_exp2f(0.01f * d1));
        p2.y = pkh(__builtin_amdgcn_exp2f(0.01f * d2), __builtin_amdgcn_exp2f(0.01f * d3));
        *(uint2*)&e1t[hh * 4096 + off] = p1;
        *(uint2*)&e2t[hh * 4096 + off] = p2;
    }
#pragma unroll
    for (int q = 0; q < 16; q++) {
        int idx = t + q * 256;                // 0..4095
        int r = idx >> 7, wd = idx & 127;
        mrow[r * 131 + wd] = mbits[(size_t)(i0 + r) * 128 + wd];
    }
    __syncthreads();

    int lane = t & 63, w = t >> 6;
    int jh = w & 1, ch = w >> 1;
    int rowl = lane & 31, jsub = (lane >> 5) * 8;

    unsigned int AcPk[2], BcPk[2];
    float lacc[2] = {0.f, 0.f};
#pragma unroll
    for (int hh = 0; hh < 2; hh++) {
        float sL = srcT[(size_t)(k0 + hh) * NN + i0 + rowl];
        float xm = sL + (hh ? Dv1 : Dv0);
        float mL = fmaxf(xm, 0.01f * xm);
        float Acf = __builtin_amdgcn_exp2f(xm - mL);
        float Bcf = __builtin_amdgcn_exp2f(fmaf(0.01f, xm, -mL));
        AcPk[hh] = pkh(Acf, Acf);
        BcPk[hh] = pkh(Bcf, Bcf);
    }

    f32x16 acc[2][4];
#pragma unroll
    for (int hh = 0; hh < 2; hh++)
#pragma unroll
        for (int nt = 0; nt < 4; nt++)
#pragma unroll
            for (int r = 0; r < 16; r++) acc[hh][nt][r] = 0.f;

    const unsigned short* e1b0 = e1t;
    const unsigned short* e1b1 = e1t + 4096;
    const unsigned short* e2b0 = e2t;
    const unsigned short* e2b1 = e2t + 4096;

    for (int jj0 = 0; jj0 < 64; jj0++) {
        int jbg = jh * 64 + jj0;
        unsigned int word = mrow[rowl * 131 + jbg];
#pragma unroll
        for (int s = 0; s < 2; s++) {
            int j16 = jbg * 2 + s;
            unsigned int mb = (word >> (s * 16 + jsub)) & 0xffu;
            unsigned int mw[4];
#pragma unroll
            for (int jp = 0; jp < 4; jp++) {
                unsigned int u2 = (mb >> (2 * jp)) & 3u;
                mw[jp] = ((u2 * 0x8001u) & 0x10001u) * 0xffffu;
            }
            int eoff = j16 * 16 + jsub;
            union { unsigned int u[4]; h16x8 v; } P[2];
            {
                uint4 E1 = *(const uint4*)&e1b0[eoff];
                uint4 E2 = *(const uint4*)&e2b0[eoff];
                unsigned int v0 = h2max(h2mul(E1.x, AcPk[0]), h2mul(E2.x, BcPk[0])) & mw[0];
                unsigned int v1 = h2max(h2mul(E1.y, AcPk[0]), h2mul(E2.y, BcPk[0])) & mw[1];
                unsigned int v2 = h2max(h2mul(E1.z, AcPk[0]), h2mul(E2.z, BcPk[0])) & mw[2];
                unsigned int v3 = h2max(h2mul(E1.w, AcPk[0]), h2mul(E2.w, BcPk[0])) & mw[3];
                lacc[0] = h2dot1(v0, lacc[0]);
                lacc[0] = h2dot1(v1, lacc[0]);
                lacc[0] = h2dot1(v2, lacc[0]);
                lacc[0] = h2dot1(v3, lacc[0]);
                P[0].u[0] = v0; P[0].u[1] = v1; P[0].u[2] = v2; P[0].u[3] = v3;
            }
            {
                uint4 E1 = *(const uint4*)&e1b1[eoff];
                uint4 E2 = *(const uint4*)&e2b1[eoff];
                unsigned int v0 = h2max(h2mul(E1.x, AcPk[1]), h2mul(E2.x, BcPk[1])) & mw[0];
                unsigned int v1 = h2max(h2mul(E1.y, AcPk[1]), h2mul(E2.y, BcPk[1])) & mw[1];
                unsigned int v2 = h2max(h2mul(E1.z, AcPk[1]), h2mul(E2.z, BcPk[1])) & mw[2];
                unsigned int v3 = h2max(h2mul(E1.w, AcPk[1]), h2mul(E2.w, BcPk[1])) & mw[3];
                lacc[1] = h2dot1(v0, lacc[1]);
                lacc[1] = h2dot1(v1, lacc[1]);
                lacc[1] = h2dot1(v2, lacc[1]);
                lacc[1] = h2dot1(v3, lacc[1]);
                P[1].u[0] = v0; P[1].u[1] = v1; P[1].u[2] = v2; P[1].u[3] = v3;
            }
            const h16x8* bp = &HB16[(size_t)j16 * 512 + (ch * 4) * 64 + lane];
#pragma unroll
            for (int nt = 0; nt < 4; nt++) {
                h16x8 bv = bp[nt * 64];
                acc[0][nt] = __builtin_amdgcn_mfma_f32_32x32x16_f16(P[0].v, bv, acc[0][nt], 0, 0, 0);
                acc[1][nt] = __builtin_amdgcn_mfma_f32_32x32x16_f16(P[1].v, bv, acc[1][nt], 0, 0, 0);
            }
        }
    }

    // row sums: lanes r and r+32 cover disjoint j-subranges of the same row
    lacc[0] += __shfl_xor(lacc[0], 32);
    lacc[1] += __shfl_xor(lacc[1], 32);
    if (ch == 0 && lane < 32) {
        l_all[jh][0][lane] = lacc[0];
        l_all[jh][1][lane] = lacc[1];
    }
    __syncthreads();  // l_all visible; loop-phase LDS dead
    if (t < 32) {
#pragma unroll
        for (int hh = 0; hh < 2; hh++) {
            float lt = l_all[0][hh][t] + l_all[1][hh][t];
            linv_l[hh][t] = (lt > 0.f) ? 1.f / lt : 0.f;  // isolated row -> 0
        }
    }
    __syncthreads();

    // epilogue: two per-head rounds, 32KB accbuf each
#pragma unroll
    for (int r = 0; r < 2; r++) {
        if (jh == 1) {
#pragma unroll
            for (int nt = 0; nt < 4; nt++) {
                float* dp = accbuf + (size_t)((ch * 4 + nt) * 16) * 64 + lane;
#pragma unroll
                for (int reg = 0; reg < 16; reg++) dp[reg * 64] = acc[r][nt][reg];
            }
        }
        __syncthreads();
        if (jh == 0) {
            int khead = k0 + r;
#pragma unroll
            for (int nt = 0; nt < 4; nt++) {
                const float* sp = accbuf + (size_t)((ch * 4 + nt) * 16) * 64 + lane;
                int c = (ch * 4 + nt) * 32 + (lane & 31);
#pragma unroll
                for (int reg = 0; reg < 16; reg++) {
                    int rowloc = (reg & 3) + 8 * (reg >> 2) + 4 * (lane >> 5);
                    float v = (acc[r][nt][reg] + sp[reg * 64]) * linv_l[r][rowloc];
                    int i = i0 + rowloc;
                    if (MODE == 1) {
                        v += h[(size_t)i * HH + c];
                        v = (v > 0.f) ? v : (__expf(v) - 1.f);  // elu
                        ((short*)outp)[(size_t)i * KH + (size_t)khead * HH + c] = f2bf(v);
                    } else {
                        ((short*)outp)[(size_t)khead * NN * HH + (size_t)i * HH + c] = f2bf(v);
                    }
                }
            }
        }
        if (r == 0) __syncthreads();
    }
}

// ---------------- elu(avg of heads) column partial sums (bf16 planes) --------
__global__ void colsum_kernel(const float* __restrict__ h2,
                              const short* __restrict__ heads,
                              float* __restrict__ partial) {
    int c = threadIdx.x;
    int b = blockIdx.x;
    float s = 0.f;
    for (int il = 0; il < 64; il++) {
        int i = b * 64 + il;
        float v = h2[(size_t)i * HH + c];
#pragma unroll
        for (int k = 0; k < KK; k++) {
            unsigned int bits = (unsigned int)(unsigned short)heads[(size_t)k * NN * HH + (size_t)i * HH + c];
            v += 0.125f * __uint_as_float(bits << 16);
        }
        s += (v > 0.f) ? v : (__expf(v) - 1.f);
    }
    partial[b * HH + c] = s;
}

__global__ void final_kernel(const float* __restrict__ partial,
                             const float* __restrict__ out_w,
                             const float* __restrict__ out_b,
                             float* __restrict__ dout) {
    __shared__ float red[256];
    int c = threadIdx.x;
    float s = 0.f;
    for (int b = 0; b < 64; b++) s += partial[b * HH + c];
    red[c] = (s / 4096.f) * out_w[c];
    __syncthreads();
    for (int off = 128; off > 0; off >>= 1) {
        if (c < off) red[c] += red[c + off];
        __syncthreads();
    }
    if (c == 0) dout[0] = red[0] + out_b[0];
}

extern "C" void kernel_launch(void* const* d_in, const int* in_sizes, int n_in,
                              void* d_out, int out_size, void* d_ws, size_t ws_size,
                              hipStream_t stream) {
    (void)in_sizes; (void)n_in; (void)out_size; (void)ws_size;
    const float* adj   = (const float*)d_in[0];
    const float* feats = (const float*)d_in[1];
    const float* W1_w  = (const float*)d_in[2];
    const float* W1_b  = (const float*)d_in[3];
    const float* a1_w  = (const float*)d_in[4];
    const float* a1_b  = (const float*)d_in[5];
    const float* W2_w  = (const float*)d_in[6];
    const float* W2_b  = (const float*)d_in[7];
    const float* a2_w  = (const float*)d_in[8];
    const float* a2_b  = (const float*)d_in[9];
    const float* out_w = (const float*)d_in[10];
    const float* out_b = (const float*)d_in[11];

    char* w = (char*)d_ws;
    const size_t MB = 1ull << 20;
    unsigned int* mbits = (unsigned int*)(w);              // 0..2MB
    short*  h1nb   = (short*)(w + 2 * MB);                 // 2..18MB  (phase 2: attn1 out bf16)
    bf16x8* h1na   = (bf16x8*)(w + 18 * MB);               // 18..34MB (phase 2: A-frag)
    short*  planes = (short*)(w + 2 * MB);                 // 2..18MB  (phase 3: head planes bf16)
    bf16x8* Bfeats = (bf16x8*)(w + 34 * MB);               // 34..38MB (phase 1)
    float*  h2     = (float*)(w + 34 * MB);                // 34..38MB (phase 3)
    float*  tmp1   = (float*)(w + 38 * MB);                // 38..46MB (phase 1)
    float*  h1     = (float*)(w + 38 * MB);                // 38..42MB (phase 2; tmp1[0:4MB] dead)
    bf16x8* W1f    = (bf16x8*)(w + 42 * MB);               // 256 KB
    bf16x8* W2f    = (bf16x8*)(w + 42 * MB + 256 * 1024);  // 1 MB
    float*  srcT   = (float*)(w + 43 * MB + 256 * 1024);   // 128 KB
    float*  dstT   = (float*)(w + 43 * MB + 384 * 1024);   // 128 KB
    unsigned int* maxd_u = (unsigned int*)(w + 43 * MB + 512 * 1024);  // 32 B
    h16x8*  HB16   = (h16x8*)(w + 44 * MB);                // 44..46MB (2 MB)
    bf16x8* tmp1a  = (bf16x8*)(w + 46 * MB);               // 46..50MB
    float*  partial = (float*)(w + 50 * MB);               // 64 KB

    // --- phase 1: h1 = (A @ feats) @ W1^T + b1 ---
    pack_mask_kernel<<<NN, 256, 0, stream>>>(adj, mbits);
    cvt_b_frag_kernel<FF><<<NN / 32, 256, 0, stream>>>(feats, Bfeats);
    gemm_adj_kernel<<<dim3(FF / 128, NN / 64), 256, 0, stream>>>(
        mbits, Bfeats, tmp1, NN / 32, FF / 16, FF);
    cvt_a_frag_kernel<float><<<NN / 16, 256, 0, stream>>>(tmp1, tmp1a, FF);
    cvt_bt_frag_kernel<<<HH / 16, 256, 0, stream>>>(W1_w, W1f, FF, HH / 16);
    gemm_frag_kernel<<<dim3(HH / 128, NN / 64), 256, 0, stream>>>(
        tmp1a, W1f, W1_b, h1, FF / 32, HH / 16, HH);

    // --- phase 2: layer-1 attention -> h1nb (bf16), then h2 ---
    (void)hipMemsetAsync(maxd_u, 0, KK * sizeof(unsigned int), stream);
    prep_kernel<<<NN / 32, 256, 0, stream>>>(h1, a1_w, a1_b, HB16, srcT, dstT, maxd_u);
    attn32_kernel<1><<<dim3(NN / 32, KK / 2), 256, 0, stream>>>(
        h1, srcT, dstT, maxd_u, mbits, HB16, h1nb);
    cvt_a_frag_kernel<short><<<NN / 16, 256, 0, stream>>>(h1nb, h1na, KH);
    cvt_bt_frag_kernel<<<HH / 16, 256, 0, stream>>>(W2_w, W2f, KH, HH / 16);
    gemm_frag_kernel<<<dim3(HH / 128, NN / 64), 256, 0, stream>>>(
        h1na, W2f, W2_b, h2, KH / 32, HH / 16, HH);

    // --- phase 3: layer-2 attention -> bf16 head planes, reduce ---
    (void)hipMemsetAsync(maxd_u, 0, KK * sizeof(unsigned int), stream);
    prep_kernel<<<NN / 32, 256, 0, stream>>>(h2, a2_w, a2_b, HB16, srcT, dstT, maxd_u);
    attn32_kernel<2><<<dim3(NN / 32, KK / 2), 256, 0, stream>>>(
        h2, srcT, dstT, maxd_u, mbits, HB16, planes);
    colsum_kernel<<<64, 256, 0, stream>>>(h2, planes, partial);
    final_kernel<<<1, 256, 0, stream>>>(partial, out_w, out_b, (float*)d_out);
}